// Round 10
// baseline (578.106 us; speedup 1.0000x reference)
//
#include <hip/hip_runtime.h>
#include <limits.h>

#pragma clang fp contract(off)

#define NB 512
#define NC 151
#define KDIM 4096
#define KS 8
#define KCH (KDIM/KS)      // 512
#define GRB 16             // gemm rows per block
#define PST 152            // padded row stride (floats), 16B-aligned rows
#define NK 16              // commits per round
#define NL 16              // cached top-list depth per row
#define NMS_TH 0.3f

typedef unsigned long long ull;

// ---------------- DPP wave64 reductions ----------------
template <int CTRL>
__device__ __forceinline__ int dpp_i(int identity, int x) {
  return __builtin_amdgcn_update_dpp(identity, x, CTRL, 0xF, 0xF, false);
}
__device__ __forceinline__ float wave_max_bcast(float x) {
  const int ID = __float_as_int(-3.4e38f);
  x = fmaxf(x, __int_as_float(dpp_i<0x111>(ID, __float_as_int(x))));  // row_shr:1
  x = fmaxf(x, __int_as_float(dpp_i<0x112>(ID, __float_as_int(x))));  // row_shr:2
  x = fmaxf(x, __int_as_float(dpp_i<0x114>(ID, __float_as_int(x))));  // row_shr:4
  x = fmaxf(x, __int_as_float(dpp_i<0x118>(ID, __float_as_int(x))));  // row_shr:8
  x = fmaxf(x, __int_as_float(dpp_i<0x142>(ID, __float_as_int(x))));  // row_bcast:15
  x = fmaxf(x, __int_as_float(dpp_i<0x143>(ID, __float_as_int(x))));  // row_bcast:31
  return __int_as_float(__builtin_amdgcn_readlane(__float_as_int(x), 63));
}
__device__ __forceinline__ int wave_min_bcast_i(int x) {
  int y;
  y = dpp_i<0x111>(INT_MAX, x); x = (x < y) ? x : y;
  y = dpp_i<0x112>(INT_MAX, x); x = (x < y) ? x : y;
  y = dpp_i<0x114>(INT_MAX, x); x = (x < y) ? x : y;
  y = dpp_i<0x118>(INT_MAX, x); x = (x < y) ? x : y;
  y = dpp_i<0x142>(INT_MAX, x); x = (x < y) ? x : y;
  y = dpp_i<0x143>(INT_MAX, x); x = (x < y) ? x : y;
  return __builtin_amdgcn_readlane(x, 63);
}

// exact reference IoU arithmetic (fp contract off file-wide)
__device__ __forceinline__ bool overlap_ge(const float4& c, const float4& o) {
  float areaC = (c.z - c.x + 1.0f) * (c.w - c.y + 1.0f);
  float areaJ = (o.z - o.x + 1.0f) * (o.w - o.y + 1.0f);
  float iw = fminf(c.z, o.z) - fmaxf(c.x, o.x) + 1.0f;
  float ih = fminf(c.w, o.w) - fmaxf(c.y, o.y) + 1.0f;
  iw = fmaxf(iw, 0.0f); ih = fmaxf(ih, 0.0f);
  float inter = iw * ih;
  float uni = areaC + areaJ - inter;
  return inter / uni >= NMS_TH;
}

__device__ __forceinline__ bool mbit(const unsigned m[5], int c) {
  bool r = false;
#pragma unroll
  for (int k = 0; k < 5; ++k) r = (k == (c >> 5)) ? (((m[k] >> (c & 31)) & 1u) != 0) : r;
  return r;
}

// ---------------- kernel 1: fused GEMM split-K partials + boxes transpose ----------------
#define TPB_GEMM 256
#define NTR ((NB * NC + 191) / 192)   // 403
__global__ __launch_bounds__(192) void gemm_fused(
    const float* __restrict__ A, const float* __restrict__ W,
    const float* __restrict__ boxes, float* __restrict__ part, float* __restrict__ bt)
{
  if (blockIdx.x >= TPB_GEMM) {
    int i = (blockIdx.x - TPB_GEMM) * 192 + threadIdx.x;
    if (i < NB * NC) {
      int r = i / NC, c = i - r * NC;
      float4 v = *(const float4*)(boxes + (size_t)i * 4);      // coalesced read
      *(float4*)(bt + ((size_t)c * NB + r) * 4) = v;           // scattered write (once)
    }
    return;
  }
  __shared__ float sA[GRB * KCH];  // 32 KB
  int rb = blockIdx.x >> 3, ks = blockIdx.x & 7;
  const float* Ab = A + (size_t)rb * GRB * KDIM + (size_t)ks * KCH;
  for (int i = threadIdx.x; i < GRB * (KCH / 4); i += 192) {
    int r = i >> 7;            // KCH/4 = 128
    int k4 = i & 127;
    *(float4*)(sA + r * KCH + k4 * 4) = *(const float4*)(Ab + (size_t)r * KDIM + k4 * 4);
  }
  __syncthreads();
  int c = threadIdx.x;
  if (c < NC) {
    const float* wp = W + (size_t)ks * KCH * NC + c;
    float acc[GRB];
#pragma unroll
    for (int r = 0; r < GRB; ++r) acc[r] = 0.f;
    float w0 = wp[0], w1 = wp[NC], w2 = wp[2 * NC], w3 = wp[3 * NC];
    for (int k4 = 0; k4 < KCH / 4; ++k4) {
      int kn = (k4 + 1 < KCH / 4) ? (k4 + 1) : k4;     // clamp: re-read last (no OOB)
      const float* q = wp + (size_t)(4 * kn) * NC;
      float n0 = q[0], n1 = q[NC], n2 = q[2 * NC], n3 = q[3 * NC];
#pragma unroll
      for (int r = 0; r < GRB; ++r) {
        float4 a = *(const float4*)(sA + r * KCH + k4 * 4);  // broadcast read
        acc[r] = fmaf(a.x, w0, acc[r]);
        acc[r] = fmaf(a.y, w1, acc[r]);
        acc[r] = fmaf(a.z, w2, acc[r]);
        acc[r] = fmaf(a.w, w3, acc[r]);
      }
      w0 = n0; w1 = n1; w2 = n2; w3 = n3;
    }
    float* o = part + ((size_t)ks * NB + (size_t)rb * GRB) * PST + c;
#pragma unroll
    for (int r = 0; r < GRB; ++r) o[(size_t)r * PST] = acc[r];
  }
}

// ---------------- kernel 2: reduce + obj_dists + softmax probs + top-16 list ----------------
__global__ __launch_bounds__(64) void prep_kernel(
    const float* __restrict__ part, const float* __restrict__ bias,
    float* __restrict__ out, float* __restrict__ lp, float* __restrict__ tl)
{
  int j = blockIdx.x * 64 + threadIdx.x;
  if (j >= NB) return;
  float* pr = lp + (size_t)j * PST;
  float* orow = out + (size_t)j * NC;

  float m_ = -3.4e38f;
  for (int c4 = 0; c4 < PST / 4; ++c4) {
    float x0 = 0.f, x1 = 0.f, x2 = 0.f, x3 = 0.f;
#pragma unroll
    for (int ks = 0; ks < KS; ++ks) {
      const float4 v = *(const float4*)(part + ((size_t)ks * NB + j) * PST + c4 * 4);
      x0 += v.x; x1 += v.y; x2 += v.z; x3 += v.w;
    }
    int c = c4 * 4;
    x0 += bias[c];
    if (c + 1 < NC) x1 += bias[c + 1];
    if (c + 2 < NC) x2 += bias[c + 2];
    if (c + 3 < NC) x3 += bias[c + 3];
    float4 st; st.x = x0; st.y = (c + 1 < NC) ? x1 : -3.4e38f;
    st.z = (c + 2 < NC) ? x2 : -3.4e38f; st.w = (c + 3 < NC) ? x3 : -3.4e38f;
    *(float4*)(pr + c4 * 4) = st;
    orow[c] = x0;
    if (c + 1 < NC) orow[c + 1] = x1;
    if (c + 2 < NC) orow[c + 2] = x2;
    if (c + 3 < NC) orow[c + 3] = x3;
    m_ = fmaxf(m_, st.x); m_ = fmaxf(m_, st.y);
    m_ = fmaxf(m_, st.z); m_ = fmaxf(m_, st.w);
  }
  float s_ = 0.f;
  for (int c4 = 0; c4 < PST / 4; ++c4) {
    float4 v = *(const float4*)(pr + c4 * 4);
    s_ += expf(v.x - m_); s_ += expf(v.y - m_);
    s_ += expf(v.z - m_); s_ += expf(v.w - m_);    // pad: exp(-huge)=0
  }
  float lv[NL]; int lc[NL];
#pragma unroll
  for (int t = 0; t < NL; ++t) { lv[t] = -3.4e38f; lc[t] = 0; }
  for (int c4 = 0; c4 < PST / 4; ++c4) {
    float4 v = *(const float4*)(pr + c4 * 4);
    int c = c4 * 4;
    float p0 = (c == 0) ? 0.f : expf(v.x - m_) / s_;
    float p1 = expf(v.y - m_) / s_;
    float p2 = expf(v.z - m_) / s_;
    float p3 = expf(v.w - m_) / s_;
    float4 st; st.x = p0; st.y = p1; st.z = p2; st.w = p3;   // pad -> 0
    *(float4*)(pr + c4 * 4) = st;
#pragma unroll
    for (int u = 0; u < 4; ++u) {
      float pv = (u == 0) ? p0 : (u == 1) ? p1 : (u == 2) ? p2 : p3;
      int cc = c + u;
      if (pv > 0.f && pv > lv[NL - 1]) {
        lv[NL - 1] = pv; lc[NL - 1] = cc;
#pragma unroll
        for (int q = NL - 1; q > 0; --q) {
          if (lv[q] > lv[q - 1]) {
            float tv = lv[q]; lv[q] = lv[q - 1]; lv[q - 1] = tv;
            int tc = lc[q]; lc[q] = lc[q - 1]; lc[q - 1] = tc;
          }
        }
      }
    }
  }
  float* tr = tl + (size_t)j * (2 * NL);
#pragma unroll
  for (int t = 0; t < NL; ++t) { tr[t] = lv[t]; tr[NL + t] = __int_as_float(lc[t]); }
}

// fallback gemm (ws too small)
__global__ __launch_bounds__(192) void gemm_full(
    const float* __restrict__ A, const float* __restrict__ W,
    const float* __restrict__ bias, float* __restrict__ out)
{
  int c = threadIdx.x;
  int r0 = blockIdx.x * 4;
  if (c >= NC) return;
  const float* a = A + (size_t)r0 * KDIM;
  const float* wp = W + c;
  float a0 = 0.f, a1 = 0.f, a2 = 0.f, a3 = 0.f;
#pragma unroll 8
  for (int k = 0; k < KDIM; ++k) {
    float w = wp[(size_t)k * NC];
    a0 = fmaf(a[k],            w, a0);
    a1 = fmaf(a[k + KDIM],     w, a1);
    a2 = fmaf(a[k + 2 * KDIM], w, a2);
    a3 = fmaf(a[k + 3 * KDIM], w, a3);
  }
  float bb = bias[c];
  out[(size_t)(r0 + 0) * NC + c] = a0 + bb;
  out[(size_t)(r0 + 1) * NC + c] = a1 + bb;
  out[(size_t)(r0 + 2) * NC + c] = a2 + bb;
  out[(size_t)(r0 + 3) * NC + c] = a3 + bb;
}

// ---------------- Multi-commit greedy NMS decode (K=16, event-driven recompute) ----------------
// Invariant at round start (unretired, unstuck rows): rowmax>0 and argcls unmasked.
// Candidate can only change when mask[argcls] fires -> scan 16-list; if exhausted,
// cheap max-only rescan over stored probs (no insert-refill, no transcendentals).
template <bool FAST>
__global__ __launch_bounds__(512) void decode_kernel(
    const float* __restrict__ lp, const float* __restrict__ tl,
    const float* __restrict__ boxes /* FAST: bt [NC][NB][4]; else raw */,
    float* __restrict__ commits)
{
  __shared__ ull cand[NB];    // 4 KB
  __shared__ int swin[NK];    // packed (row<<8)|cls, -1 = invalid
  __shared__ int s_p;
  const int j = threadIdx.x;
  const int lane = j & 63;

  float lv[NL]; int lc[NL];
  float m_ = 0.f, s_ = 1.f;
  const float* xr = FAST ? (lp + (size_t)j * PST) : (lp + (size_t)j * NC);

  if (FAST) {
    const float4* tl4 = (const float4*)(tl + (size_t)j * (2 * NL));
#pragma unroll
    for (int q = 0; q < NL / 4; ++q) {
      float4 v = tl4[q];
      lv[4 * q] = v.x; lv[4 * q + 1] = v.y; lv[4 * q + 2] = v.z; lv[4 * q + 3] = v.w;
    }
#pragma unroll
    for (int q = 0; q < NL / 4; ++q) {
      float4 v = tl4[NL / 4 + q];
      lc[4 * q] = __float_as_int(v.x); lc[4 * q + 1] = __float_as_int(v.y);
      lc[4 * q + 2] = __float_as_int(v.z); lc[4 * q + 3] = __float_as_int(v.w);
    }
  } else {
#pragma unroll
    for (int t = 0; t < NL; ++t) { lv[t] = -3.4e38f; lc[t] = 0; }
    m_ = xr[0];
    for (int c = 1; c < NC; ++c) m_ = fmaxf(m_, xr[c]);
    s_ = 0.f;
    for (int c = 0; c < NC; ++c) s_ += expf(xr[c] - m_);
    for (int c = 1; c < NC; ++c) {
      float v = expf(xr[c] - m_) / s_;
      if (v > lv[NL - 1]) {
        lv[NL - 1] = v; lc[NL - 1] = c;
#pragma unroll
        for (int q = NL - 1; q > 0; --q) {
          if (lv[q] > lv[q - 1]) {
            float tv = lv[q]; lv[q] = lv[q - 1]; lv[q - 1] = tv;
            int tc = lc[q]; lc[q] = lc[q - 1]; lc[q - 1] = tc;
          }
        }
      }
    }
  }

  float rowmax; int argcls; bool zstuck = false;
  if (lv[0] > 0.f) { rowmax = lv[0]; argcls = lc[0]; }
  else { rowmax = 0.f; argcls = 0; zstuck = true; }

  unsigned mask[5] = {0, 0, 0, 0, 0};
  bool retired = false;
  int post_min = INT_MAX;
  int commitcls = 0;
  int committed = 0;

  while (committed < NB) {
    cand[j] = ((ull)(unsigned)__float_as_int(rowmax) << 32) | (unsigned)(j * NC + argcls);
    __syncthreads();   // A

    if (j < 64) {
      // ---- wave 0: gather + exact top-16 extraction, publish per-pop ----
      float vv[8]; int vi[8];
#pragma unroll
      for (int t = 0; t < 8; ++t) {
        ull k = cand[lane + 64 * t];
        vv[t] = __int_as_float((int)(k >> 32));
        vi[t] = (int)(unsigned)(k & 0xFFFFFFFFu);
      }
      float lmv = vv[0]; int lmi = vi[0];
#pragma unroll
      for (int t = 1; t < 8; ++t) if (vv[t] > lmv) { lmv = vv[t]; lmi = vi[t]; }

      unsigned okm = 0;
      int kmax = NB - committed; if (kmax > NK) kmax = NK;
      bool stop = false;
#pragma unroll
      for (int t = 0; t < NK; ++t) {
        if (t >= kmax || stop) {
          if (lane == 0) swin[t] = -1;
          continue;
        }
        float gv = wave_max_bcast(lmv);
        ull tied = __ballot(lmv == gv);
        int gi;
        if (__popcll(tied) == 1) {
          gi = __builtin_amdgcn_readlane(lmi, (int)__ffsll(tied) - 1);
        } else {
          gi = wave_min_bcast_i((lmv == gv) ? lmi : INT_MAX);  // exact min-flat-idx tie-break
        }
        int row = gi / NC;
        if (lane == 0) swin[t] = (row << 8) | (gi - row * NC);
        if (gv > 0.f) okm |= (1u << t); else stop = true;
        if (lmi == gi) {   // winner lane pops and rescans its 8
#pragma unroll
          for (int u = 0; u < 8; ++u) if (vi[u] == gi) vv[u] = -3.0e38f;
          lmv = vv[0]; lmi = vi[0];
#pragma unroll
          for (int u = 1; u < 8; ++u) if (vv[u] > lmv) { lmv = vv[u]; lmi = vi[u]; }
        }
      }

      // ---- chain validity: 3 pair-sets, 3 ballots (winners from LDS) ----
      int hi = lane >> 3, lo = lane & 7;
      int pT1 = swin[hi], pS1 = swin[lo];          // BA: pair (hi, lo), lo<hi
      int pT2 = swin[8 + hi];                      // BB: pair (8+hi, lo)
      int pS3 = swin[8 + lo];                      // BC: pair (8+hi, 8+lo), lo<hi
      auto supf = [&](int pT, int pS) -> bool {
        if (pT < 0 || pS < 0) return false;
        int cT = pT & 255, cS = pS & 255;
        if (cT != cS) return false;
        float4 bs, btx;
        if (FAST) {
          bs  = *(const float4*)(boxes + ((size_t)cS * NB + (pS >> 8)) * 4);
          btx = *(const float4*)(boxes + ((size_t)cT * NB + (pT >> 8)) * 4);
        } else {
          bs  = *(const float4*)(boxes + ((size_t)(pS >> 8) * NC + cS) * 4);
          btx = *(const float4*)(boxes + ((size_t)(pT >> 8) * NC + cT) * 4);
        }
        return overlap_ge(bs, btx);
      };
      bool sA2 = (lo < hi) && supf(pT1, pS1);
      bool sB2 = supf(pT2, pS1);
      bool sC2 = (lo < hi) && supf(pT2, pS3);
      ull BA = __ballot(sA2);
      ull BB = __ballot(sB2);
      ull BC = __ballot(sC2);

      unsigned validset = 1; int p = 1;
#pragma unroll
      for (int t = 1; t < 8; ++t) {
        unsigned cm = (unsigned)((BA >> (8 * t)) & 0xFF) & (validset & 0xFF);
        if (p == t && ((okm >> t) & 1u) && cm == 0u) { validset |= (1u << t); p = t + 1; }
      }
#pragma unroll
      for (int t = 8; t < NK; ++t) {
        unsigned cmlo = (unsigned)((BB >> (8 * (t - 8))) & 0xFF) & (validset & 0xFF);
        unsigned cmhi = (unsigned)((BC >> (8 * (t - 8))) & 0xFF) & ((validset >> 8) & 0xFF);
        if (p == t && ((okm >> t) & 1u) && cmlo == 0u && cmhi == 0u) {
          validset |= (1u << t); p = t + 1;
        }
      }
      if (lane == 0) s_p = p;
    }
    __syncthreads();   // B

    // ---- all threads: apply the p commits in order, two groups of 8 ----
    const int p = s_p;
#pragma unroll
    for (int g = 0; g < 2; ++g) {
      if (g * 8 < p) {
        int rows_[8], cls_[8];
        float4 cb[8], ob[8];
#pragma unroll
        for (int u = 0; u < 8; ++u) {
          int t = g * 8 + u;
          int pkv = __builtin_amdgcn_readfirstlane(swin[t]);   // uniform scalar
          rows_[u] = pkv >> 8; cls_[u] = pkv & 255;
          if (t < p) {
            if (FAST) {
              const float* btc = boxes + (size_t)cls_[u] * NB * 4;
              cb[u] = *(const float4*)(btc + (size_t)rows_[u] * 4);  // s_load (uniform)
              ob[u] = *(const float4*)(btc + (size_t)j * 4);         // lane-dense
            } else {
              cb[u] = *(const float4*)(boxes + ((size_t)rows_[u] * NC + cls_[u]) * 4);
              ob[u] = *(const float4*)(boxes + ((size_t)j * NC + cls_[u]) * 4);
            }
          }
        }
#pragma unroll
        for (int u = 0; u < 8; ++u) {
          int t = g * 8 + u;
          if (t < p) {
            if (j == rows_[u]) {
              // commit: col update overwritten by row := -1 (reference order)
              retired = true; commitcls = cls_[u]; post_min = INT_MAX;
            } else if (overlap_ge(cb[u], ob[u])) {
              if (retired) {
                post_min = (cls_[u] < post_min) ? cls_[u] : post_min;  // resurrect -1 -> 0.0
              } else {
                int c = cls_[u];
#pragma unroll
                for (int k5 = 0; k5 < 5; ++k5) if (k5 == (c >> 5)) mask[k5] |= (1u << (c & 31));
              }
            }
          }
        }
      }
    }

    // ---- event-driven candidate recompute ----
    if (retired) {
      rowmax = (post_min != INT_MAX) ? 0.0f : -1.0f;
      argcls = (post_min != INT_MAX) ? post_min : 0;
    } else if (!zstuck && mbit(mask, argcls)) {
      // my class was just suppressed: scan cached top-16
      bool found = false;
#pragma unroll
      for (int t = 0; t < NL; ++t) {
        if (!found && lv[t] > 0.f && !mbit(mask, lc[t])) {
          rowmax = lv[t]; argcls = lc[t]; found = true;
        }
      }
      if (!found) {
        // cheap max-only rescan over stored probs (FAST) / expf recompute (fallback)
        float bm = -3.4e38f; int ba = 0;
        if (FAST) {
          for (int c4 = 0; c4 < PST / 4; ++c4) {
            float4 v4 = *(const float4*)(xr + c4 * 4);   // probs; class0=0, pad=0
            int c = c4 * 4;
            float vals[4] = {v4.x, v4.y, v4.z, v4.w};
#pragma unroll
            for (int u = 0; u < 4; ++u) {
              int cc = c + u;
              float v = mbit(mask, cc) ? 0.f : vals[u];
              if (v > bm) { bm = v; ba = cc; }   // cc=0 (v=0) hits first; pads never exceed
            }
          }
        } else {
          for (int c = 0; c < NC; ++c) {
            float v;
            if (c == 0) v = 0.f;
            else v = mbit(mask, c) ? 0.f : (expf(xr[c] - m_) / s_);
            if (v > bm) { bm = v; ba = c; }
          }
        }
        rowmax = bm; argcls = ba;
        if (!(bm > 0.f)) zstuck = true;   // all-zero row: candidate stable forever
      }
    }
    // zstuck: keep (rowmax=0, argcls) — values never increase for this row

    committed += p;
  }

  commits[j] = (float)commitcls;
}

extern "C" void kernel_launch(void* const* d_in, const int* in_sizes, int n_in,
                              void* d_out, int out_size, void* d_ws, size_t ws_size,
                              hipStream_t stream) {
  const float* A     = (const float*)d_in[0];   // obj_fmap [512,4096]
  const float* boxes = (const float*)d_in[1];   // boxes_per_cls [512,151,4]
  const float* W     = (const float*)d_in[2];   // [4096,151]
  const float* bias  = (const float*)d_in[3];   // [151]
  float* out = (float*)d_out;                   // [512*151] obj_dists ++ [512] commits

  const size_t np = (size_t)KS * NB * PST;      // part
  const size_t nl = (size_t)NB * PST;           // lp
  const size_t nt = (size_t)NB * (2 * NL);      // tl
  const size_t nb = (size_t)NC * NB * 4;        // bt
  const size_t need = (np + nl + nt + nb) * 4;

  if (ws_size >= need) {
    float* part = (float*)d_ws;
    float* lp   = part + np;
    float* tl   = lp + nl;
    float* bt   = tl + nt;
    gemm_fused<<<TPB_GEMM + NTR, 192, 0, stream>>>(A, W, boxes, part, bt);
    prep_kernel<<<NB / 64, 64, 0, stream>>>(part, bias, out, lp, tl);
    decode_kernel<true><<<1, NB, 0, stream>>>(lp, tl, bt, out + NB * NC);
  } else {
    gemm_full<<<NB / 4, 192, 0, stream>>>(A, W, bias, out);
    decode_kernel<false><<<1, NB, 0, stream>>>(out, nullptr, boxes, out + NB * NC);
  }
}

// Round 11
// 507.639 us; speedup vs baseline: 1.1388x; 1.1388x over previous
//
#include <hip/hip_runtime.h>
#include <limits.h>

#pragma clang fp contract(off)

#define NB 512
#define NC 151
#define KDIM 4096
#define KS 8
#define KCH (KDIM/KS)      // 512
#define GRB 16             // gemm rows per block
#define PST 152            // padded row stride (floats), 16B-aligned rows
#define NK 16              // commits per round
#define NL 16              // cached top-list depth per row
#define NMS_TH 0.3f

typedef unsigned long long ull;

// ---------------- DPP wave64 reductions ----------------
template <int CTRL>
__device__ __forceinline__ int dpp_i(int identity, int x) {
  return __builtin_amdgcn_update_dpp(identity, x, CTRL, 0xF, 0xF, false);
}
// unsigned max across 64 lanes, broadcast via readlane 63 (identity 0)
__device__ __forceinline__ unsigned wave_umax_bcast(unsigned x) {
  unsigned y;
  y = (unsigned)dpp_i<0x111>(0, (int)x); x = x > y ? x : y;   // row_shr:1
  y = (unsigned)dpp_i<0x112>(0, (int)x); x = x > y ? x : y;   // row_shr:2
  y = (unsigned)dpp_i<0x114>(0, (int)x); x = x > y ? x : y;   // row_shr:4
  y = (unsigned)dpp_i<0x118>(0, (int)x); x = x > y ? x : y;   // row_shr:8
  y = (unsigned)dpp_i<0x142>(0, (int)x); x = x > y ? x : y;   // row_bcast:15
  y = (unsigned)dpp_i<0x143>(0, (int)x); x = x > y ? x : y;   // row_bcast:31
  return (unsigned)__builtin_amdgcn_readlane((int)x, 63);
}

// exact reference IoU arithmetic (fp contract off file-wide)
__device__ __forceinline__ bool overlap_ge(const float4& c, const float4& o) {
  float areaC = (c.z - c.x + 1.0f) * (c.w - c.y + 1.0f);
  float areaJ = (o.z - o.x + 1.0f) * (o.w - o.y + 1.0f);
  float iw = fminf(c.z, o.z) - fmaxf(c.x, o.x) + 1.0f;
  float ih = fminf(c.w, o.w) - fmaxf(c.y, o.y) + 1.0f;
  iw = fmaxf(iw, 0.0f); ih = fmaxf(ih, 0.0f);
  float inter = iw * ih;
  float uni = areaC + areaJ - inter;
  return inter / uni >= NMS_TH;
}

__device__ __forceinline__ bool mbit(const unsigned m[5], int c) {
  bool r = false;
#pragma unroll
  for (int k = 0; k < 5; ++k) r = (k == (c >> 5)) ? (((m[k] >> (c & 31)) & 1u) != 0) : r;
  return r;
}

// ---------------- kernel 1: fused GEMM split-K partials + boxes transpose ----------------
#define TPB_GEMM 256
#define NTR ((NB * NC + 191) / 192)   // 403
__global__ __launch_bounds__(192) void gemm_fused(
    const float* __restrict__ A, const float* __restrict__ W,
    const float* __restrict__ boxes, float* __restrict__ part, float* __restrict__ bt)
{
  if (blockIdx.x >= TPB_GEMM) {
    int i = (blockIdx.x - TPB_GEMM) * 192 + threadIdx.x;
    if (i < NB * NC) {
      int r = i / NC, c = i - r * NC;
      float4 v = *(const float4*)(boxes + (size_t)i * 4);      // coalesced read
      *(float4*)(bt + ((size_t)c * NB + r) * 4) = v;           // scattered write (once)
    }
    return;
  }
  __shared__ float sA[GRB * KCH];  // 32 KB
  int rb = blockIdx.x >> 3, ks = blockIdx.x & 7;
  const float* Ab = A + (size_t)rb * GRB * KDIM + (size_t)ks * KCH;
  for (int i = threadIdx.x; i < GRB * (KCH / 4); i += 192) {
    int r = i >> 7;            // KCH/4 = 128
    int k4 = i & 127;
    *(float4*)(sA + r * KCH + k4 * 4) = *(const float4*)(Ab + (size_t)r * KDIM + k4 * 4);
  }
  __syncthreads();
  int c = threadIdx.x;
  if (c < NC) {
    const float* wp = W + (size_t)ks * KCH * NC + c;
    float acc[GRB];
#pragma unroll
    for (int r = 0; r < GRB; ++r) acc[r] = 0.f;
    float w0 = wp[0], w1 = wp[NC], w2 = wp[2 * NC], w3 = wp[3 * NC];
    for (int k4 = 0; k4 < KCH / 4; ++k4) {
      int kn = (k4 + 1 < KCH / 4) ? (k4 + 1) : k4;     // clamp: re-read last (no OOB)
      const float* q = wp + (size_t)(4 * kn) * NC;
      float n0 = q[0], n1 = q[NC], n2 = q[2 * NC], n3 = q[3 * NC];
#pragma unroll
      for (int r = 0; r < GRB; ++r) {
        float4 a = *(const float4*)(sA + r * KCH + k4 * 4);  // broadcast read
        acc[r] = fmaf(a.x, w0, acc[r]);
        acc[r] = fmaf(a.y, w1, acc[r]);
        acc[r] = fmaf(a.z, w2, acc[r]);
        acc[r] = fmaf(a.w, w3, acc[r]);
      }
      w0 = n0; w1 = n1; w2 = n2; w3 = n3;
    }
    float* o = part + ((size_t)ks * NB + (size_t)rb * GRB) * PST + c;
#pragma unroll
    for (int r = 0; r < GRB; ++r) o[(size_t)r * PST] = acc[r];
  }
}

// ---------------- kernel 2: reduce + obj_dists + softmax probs + top-16 list ----------------
__global__ __launch_bounds__(64) void prep_kernel(
    const float* __restrict__ part, const float* __restrict__ bias,
    float* __restrict__ out, float* __restrict__ lp, float* __restrict__ tl)
{
  int j = blockIdx.x * 64 + threadIdx.x;
  if (j >= NB) return;
  float* pr = lp + (size_t)j * PST;
  float* orow = out + (size_t)j * NC;

  float m_ = -3.4e38f;
  for (int c4 = 0; c4 < PST / 4; ++c4) {
    float x0 = 0.f, x1 = 0.f, x2 = 0.f, x3 = 0.f;
#pragma unroll
    for (int ks = 0; ks < KS; ++ks) {
      const float4 v = *(const float4*)(part + ((size_t)ks * NB + j) * PST + c4 * 4);
      x0 += v.x; x1 += v.y; x2 += v.z; x3 += v.w;
    }
    int c = c4 * 4;
    x0 += bias[c];
    if (c + 1 < NC) x1 += bias[c + 1];
    if (c + 2 < NC) x2 += bias[c + 2];
    if (c + 3 < NC) x3 += bias[c + 3];
    float4 st; st.x = x0; st.y = (c + 1 < NC) ? x1 : -3.4e38f;
    st.z = (c + 2 < NC) ? x2 : -3.4e38f; st.w = (c + 3 < NC) ? x3 : -3.4e38f;
    *(float4*)(pr + c4 * 4) = st;
    orow[c] = x0;
    if (c + 1 < NC) orow[c + 1] = x1;
    if (c + 2 < NC) orow[c + 2] = x2;
    if (c + 3 < NC) orow[c + 3] = x3;
    m_ = fmaxf(m_, st.x); m_ = fmaxf(m_, st.y);
    m_ = fmaxf(m_, st.z); m_ = fmaxf(m_, st.w);
  }
  float s_ = 0.f;
  for (int c4 = 0; c4 < PST / 4; ++c4) {
    float4 v = *(const float4*)(pr + c4 * 4);
    s_ += expf(v.x - m_); s_ += expf(v.y - m_);
    s_ += expf(v.z - m_); s_ += expf(v.w - m_);    // pad: exp(-huge)=0
  }
  float lv[NL]; int lc[NL];
#pragma unroll
  for (int t = 0; t < NL; ++t) { lv[t] = -3.4e38f; lc[t] = 0; }
  for (int c4 = 0; c4 < PST / 4; ++c4) {
    float4 v = *(const float4*)(pr + c4 * 4);
    int c = c4 * 4;
    float p0 = (c == 0) ? 0.f : expf(v.x - m_) / s_;
    float p1 = expf(v.y - m_) / s_;
    float p2 = expf(v.z - m_) / s_;
    float p3 = expf(v.w - m_) / s_;
    float4 st; st.x = p0; st.y = p1; st.z = p2; st.w = p3;   // pad -> 0
    *(float4*)(pr + c4 * 4) = st;
#pragma unroll
    for (int u = 0; u < 4; ++u) {
      float pv = (u == 0) ? p0 : (u == 1) ? p1 : (u == 2) ? p2 : p3;
      int cc = c + u;
      if (pv > 0.f && pv > lv[NL - 1]) {
        lv[NL - 1] = pv; lc[NL - 1] = cc;
#pragma unroll
        for (int q = NL - 1; q > 0; --q) {
          if (lv[q] > lv[q - 1]) {
            float tv = lv[q]; lv[q] = lv[q - 1]; lv[q - 1] = tv;
            int tc = lc[q]; lc[q] = lc[q - 1]; lc[q - 1] = tc;
          }
        }
      }
    }
  }
  float* tr = tl + (size_t)j * (2 * NL);
#pragma unroll
  for (int t = 0; t < NL; ++t) { tr[t] = lv[t]; tr[NL + t] = __int_as_float(lc[t]); }
}

// fallback gemm (ws too small)
__global__ __launch_bounds__(192) void gemm_full(
    const float* __restrict__ A, const float* __restrict__ W,
    const float* __restrict__ bias, float* __restrict__ out)
{
  int c = threadIdx.x;
  int r0 = blockIdx.x * 4;
  if (c >= NC) return;
  const float* a = A + (size_t)r0 * KDIM;
  const float* wp = W + c;
  float a0 = 0.f, a1 = 0.f, a2 = 0.f, a3 = 0.f;
#pragma unroll 8
  for (int k = 0; k < KDIM; ++k) {
    float w = wp[(size_t)k * NC];
    a0 = fmaf(a[k],            w, a0);
    a1 = fmaf(a[k + KDIM],     w, a1);
    a2 = fmaf(a[k + 2 * KDIM], w, a2);
    a3 = fmaf(a[k + 3 * KDIM], w, a3);
  }
  float bb = bias[c];
  out[(size_t)(r0 + 0) * NC + c] = a0 + bb;
  out[(size_t)(r0 + 1) * NC + c] = a1 + bb;
  out[(size_t)(r0 + 2) * NC + c] = a2 + bb;
  out[(size_t)(r0 + 3) * NC + c] = a3 + bb;
}

// desc compare-exchange on u64 keys (larger first)
#define CED(a, b) { bool _s = (a) < (b); ull _x = _s ? (b) : (a); ull _y = _s ? (a) : (b); (a) = _x; (b) = _y; }

// ---------------- Multi-commit greedy NMS decode (K=16, sorted-shift pop) ----------------
// cand key: (orderable(value) << 32) | (0xFFFFFFFF - flatidx) — u64 order ==
// (value desc, flatidx asc), exactly the reference argmax tie-break.
// Wave0: gather 8 keys/lane -> Batcher sort desc (19 CE, off pop chain) ->
// 16 pops, each: u32 DPP-max over heads + winner resolve + 1-level shift-down.
template <bool FAST>
__global__ __launch_bounds__(512) void decode_kernel(
    const float* __restrict__ lp, const float* __restrict__ tl,
    const float* __restrict__ boxes /* FAST: bt [NC][NB][4]; else raw */,
    float* __restrict__ commits)
{
  __shared__ ull cand[NB];    // 4 KB
  __shared__ int swin[NK];    // packed (row<<8)|cls, -1 = invalid
  __shared__ int s_p;
  const int j = threadIdx.x;
  const int lane = j & 63;

  float lv[NL]; int lc[NL];
  float m_ = 0.f, s_ = 1.f;
  const float* xr = FAST ? (lp + (size_t)j * PST) : (lp + (size_t)j * NC);

  if (FAST) {
    const float4* tl4 = (const float4*)(tl + (size_t)j * (2 * NL));
#pragma unroll
    for (int q = 0; q < NL / 4; ++q) {
      float4 v = tl4[q];
      lv[4 * q] = v.x; lv[4 * q + 1] = v.y; lv[4 * q + 2] = v.z; lv[4 * q + 3] = v.w;
    }
#pragma unroll
    for (int q = 0; q < NL / 4; ++q) {
      float4 v = tl4[NL / 4 + q];
      lc[4 * q] = __float_as_int(v.x); lc[4 * q + 1] = __float_as_int(v.y);
      lc[4 * q + 2] = __float_as_int(v.z); lc[4 * q + 3] = __float_as_int(v.w);
    }
  } else {
#pragma unroll
    for (int t = 0; t < NL; ++t) { lv[t] = -3.4e38f; lc[t] = 0; }
    m_ = xr[0];
    for (int c = 1; c < NC; ++c) m_ = fmaxf(m_, xr[c]);
    s_ = 0.f;
    for (int c = 0; c < NC; ++c) s_ += expf(xr[c] - m_);
    for (int c = 1; c < NC; ++c) {
      float v = expf(xr[c] - m_) / s_;
      if (v > lv[NL - 1]) {
        lv[NL - 1] = v; lc[NL - 1] = c;
#pragma unroll
        for (int q = NL - 1; q > 0; --q) {
          if (lv[q] > lv[q - 1]) {
            float tv = lv[q]; lv[q] = lv[q - 1]; lv[q - 1] = tv;
            int tc = lc[q]; lc[q] = lc[q - 1]; lc[q - 1] = tc;
          }
        }
      }
    }
  }

  float rowmax; int argcls; bool zstuck = false;
  if (lv[0] > 0.f) { rowmax = lv[0]; argcls = lc[0]; }
  else { rowmax = 0.f; argcls = 0; zstuck = true; }

  unsigned mask[5] = {0, 0, 0, 0, 0};
  bool retired = false;
  int post_min = INT_MAX;
  int commitcls = 0;
  int committed = 0;

  while (committed < NB) {
    {
      unsigned u = __float_as_uint(rowmax);
      u ^= (u & 0x80000000u) ? 0xFFFFFFFFu : 0x80000000u;   // orderable encoding
      cand[j] = ((ull)u << 32) | (unsigned)(0xFFFFFFFFu - (unsigned)(j * NC + argcls));
    }
    __syncthreads();   // A

    if (j < 64) {
      // ---- gather 8 keys, per-lane Batcher sort desc (depth 6, 19 CE) ----
      ull k0 = cand[lane], k1 = cand[lane + 64], k2 = cand[lane + 128], k3 = cand[lane + 192];
      ull k4 = cand[lane + 256], k5 = cand[lane + 320], k6 = cand[lane + 384], k7 = cand[lane + 448];
      CED(k0, k1) CED(k2, k3) CED(k0, k2) CED(k1, k3) CED(k1, k2)   // sort4 lo
      CED(k4, k5) CED(k6, k7) CED(k4, k6) CED(k5, k7) CED(k5, k6)   // sort4 hi
      CED(k0, k4) CED(k1, k5) CED(k2, k6) CED(k3, k7)               // odd-even merge
      CED(k2, k4) CED(k3, k5)
      CED(k1, k2) CED(k3, k4) CED(k5, k6)

      // ---- 16 pops: DPP-umax over heads + shift-down ----
      unsigned okm = 0;
      int kmax = NB - committed; if (kmax > NK) kmax = NK;
      bool stop = false;
#pragma unroll
      for (int t = 0; t < NK; ++t) {
        if (t >= kmax || stop) {
          if (lane == 0) swin[t] = -1;
          continue;
        }
        unsigned hv = (unsigned)(k0 >> 32);
        unsigned gv = wave_umax_bcast(hv);
        bool eq = (hv == gv);
        ull tb = __ballot(eq);
        unsigned mylo = (unsigned)k0;
        unsigned glo;
        if (__popcll(tb) == 1) {
          glo = (unsigned)__builtin_amdgcn_readlane((int)mylo, (int)__ffsll(tb) - 1);
        } else {
          glo = wave_umax_bcast(eq ? mylo : 0u);   // max(~flat) = min flat idx (exact tie-break)
        }
        int gi = (int)(0xFFFFFFFFu - glo);
        bool iswin = eq && (mylo == glo);
        if (iswin) { k0 = k1; k1 = k2; k2 = k3; k3 = k4; k4 = k5; k5 = k6; k6 = k7; k7 = 0; }
        int row = gi / NC;                          // off pop chain (overlaps next reduce)
        if (lane == 0) swin[t] = (row << 8) | (gi - row * NC);
        if (gv > 0x80000000u) okm |= (1u << t); else stop = true;   // orderable(0.0)=0x80000000
      }

      // ---- chain validity: 3 pair-sets, 3 ballots (winners from LDS) ----
      int hi = lane >> 3, lo = lane & 7;
      int pT1 = swin[hi], pS1 = swin[lo];          // BA: pair (hi, lo), lo<hi
      int pT2 = swin[8 + hi];                      // BB: pair (8+hi, lo)
      int pS3 = swin[8 + lo];                      // BC: pair (8+hi, 8+lo), lo<hi
      auto supf = [&](int pT, int pS) -> bool {
        if (pT < 0 || pS < 0) return false;
        int cT = pT & 255, cS = pS & 255;
        if (cT != cS) return false;
        float4 bs, btx;
        if (FAST) {
          bs  = *(const float4*)(boxes + ((size_t)cS * NB + (pS >> 8)) * 4);
          btx = *(const float4*)(boxes + ((size_t)cT * NB + (pT >> 8)) * 4);
        } else {
          bs  = *(const float4*)(boxes + ((size_t)(pS >> 8) * NC + cS) * 4);
          btx = *(const float4*)(boxes + ((size_t)(pT >> 8) * NC + cT) * 4);
        }
        return overlap_ge(bs, btx);
      };
      bool sA2 = (lo < hi) && supf(pT1, pS1);
      bool sB2 = supf(pT2, pS1);
      bool sC2 = (lo < hi) && supf(pT2, pS3);
      ull BA = __ballot(sA2);
      ull BB = __ballot(sB2);
      ull BC = __ballot(sC2);

      unsigned validset = 1; int p = 1;
#pragma unroll
      for (int t = 1; t < 8; ++t) {
        unsigned cm = (unsigned)((BA >> (8 * t)) & 0xFF) & (validset & 0xFF);
        if (p == t && ((okm >> t) & 1u) && cm == 0u) { validset |= (1u << t); p = t + 1; }
      }
#pragma unroll
      for (int t = 8; t < NK; ++t) {
        unsigned cmlo = (unsigned)((BB >> (8 * (t - 8))) & 0xFF) & (validset & 0xFF);
        unsigned cmhi = (unsigned)((BC >> (8 * (t - 8))) & 0xFF) & ((validset >> 8) & 0xFF);
        if (p == t && ((okm >> t) & 1u) && cmlo == 0u && cmhi == 0u) {
          validset |= (1u << t); p = t + 1;
        }
      }
      if (lane == 0) s_p = p;
    }
    __syncthreads();   // B

    // ---- all threads: apply the p commits in order, two groups of 8 ----
    const int p = s_p;
#pragma unroll
    for (int g = 0; g < 2; ++g) {
      if (g * 8 < p) {
        int rows_[8], cls_[8];
        float4 cb[8], ob[8];
#pragma unroll
        for (int u = 0; u < 8; ++u) {
          int t = g * 8 + u;
          int pkv = __builtin_amdgcn_readfirstlane(swin[t]);   // uniform scalar
          rows_[u] = pkv >> 8; cls_[u] = pkv & 255;
          if (t < p) {
            if (FAST) {
              const float* btc = boxes + (size_t)cls_[u] * NB * 4;
              cb[u] = *(const float4*)(btc + (size_t)rows_[u] * 4);  // s_load (uniform)
              ob[u] = *(const float4*)(btc + (size_t)j * 4);         // lane-dense
            } else {
              cb[u] = *(const float4*)(boxes + ((size_t)rows_[u] * NC + cls_[u]) * 4);
              ob[u] = *(const float4*)(boxes + ((size_t)j * NC + cls_[u]) * 4);
            }
          }
        }
#pragma unroll
        for (int u = 0; u < 8; ++u) {
          int t = g * 8 + u;
          if (t < p) {
            if (j == rows_[u]) {
              // commit: col update overwritten by row := -1 (reference order)
              retired = true; commitcls = cls_[u]; post_min = INT_MAX;
            } else if (overlap_ge(cb[u], ob[u])) {
              if (retired) {
                post_min = (cls_[u] < post_min) ? cls_[u] : post_min;  // resurrect -1 -> 0.0
              } else {
                int c = cls_[u];
#pragma unroll
                for (int k5b = 0; k5b < 5; ++k5b) if (k5b == (c >> 5)) mask[k5b] |= (1u << (c & 31));
              }
            }
          }
        }
      }
    }

    // ---- event-driven candidate recompute ----
    if (retired) {
      rowmax = (post_min != INT_MAX) ? 0.0f : -1.0f;
      argcls = (post_min != INT_MAX) ? post_min : 0;
    } else if (!zstuck && mbit(mask, argcls)) {
      // my class was just suppressed: scan cached top-16
      bool found = false;
#pragma unroll
      for (int t = 0; t < NL; ++t) {
        if (!found && lv[t] > 0.f && !mbit(mask, lc[t])) {
          rowmax = lv[t]; argcls = lc[t]; found = true;
        }
      }
      if (!found) {
        // cheap max-only rescan over stored probs (FAST) / expf recompute (fallback)
        float bm = -3.4e38f; int ba = 0;
        if (FAST) {
          for (int c4 = 0; c4 < PST / 4; ++c4) {
            float4 v4 = *(const float4*)(xr + c4 * 4);   // probs; class0=0, pad=0
            int c = c4 * 4;
            float vals[4] = {v4.x, v4.y, v4.z, v4.w};
#pragma unroll
            for (int u = 0; u < 4; ++u) {
              int cc = c + u;
              float v = mbit(mask, cc) ? 0.f : vals[u];
              if (v > bm) { bm = v; ba = cc; }   // cc=0 (v=0) hits first; pads never exceed
            }
          }
        } else {
          for (int c = 0; c < NC; ++c) {
            float v;
            if (c == 0) v = 0.f;
            else v = mbit(mask, c) ? 0.f : (expf(xr[c] - m_) / s_);
            if (v > bm) { bm = v; ba = c; }
          }
        }
        rowmax = bm; argcls = ba;
        if (!(bm > 0.f)) zstuck = true;   // all-zero row: candidate stable forever
      }
    }
    // zstuck: keep (rowmax=0, argcls) — values never increase for this row

    committed += p;
  }

  commits[j] = (float)commitcls;
}

extern "C" void kernel_launch(void* const* d_in, const int* in_sizes, int n_in,
                              void* d_out, int out_size, void* d_ws, size_t ws_size,
                              hipStream_t stream) {
  const float* A     = (const float*)d_in[0];   // obj_fmap [512,4096]
  const float* boxes = (const float*)d_in[1];   // boxes_per_cls [512,151,4]
  const float* W     = (const float*)d_in[2];   // [4096,151]
  const float* bias  = (const float*)d_in[3];   // [151]
  float* out = (float*)d_out;                   // [512*151] obj_dists ++ [512] commits

  const size_t np = (size_t)KS * NB * PST;      // part
  const size_t nl = (size_t)NB * PST;           // lp
  const size_t nt = (size_t)NB * (2 * NL);      // tl
  const size_t nb = (size_t)NC * NB * 4;        // bt
  const size_t need = (np + nl + nt + nb) * 4;

  if (ws_size >= need) {
    float* part = (float*)d_ws;
    float* lp   = part + np;
    float* tl   = lp + nl;
    float* bt   = tl + nt;
    gemm_fused<<<TPB_GEMM + NTR, 192, 0, stream>>>(A, W, boxes, part, bt);
    prep_kernel<<<NB / 64, 64, 0, stream>>>(part, bias, out, lp, tl);
    decode_kernel<true><<<1, NB, 0, stream>>>(lp, tl, bt, out + NB * NC);
  } else {
    gemm_full<<<NB / 4, 192, 0, stream>>>(A, W, bias, out);
    decode_kernel<false><<<1, NB, 0, stream>>>(out, nullptr, boxes, out + NB * NC);
  }
}